// Round 5
// baseline (46.844 us; speedup 1.0000x reference)
//
#include <hip/hip_runtime.h>
#include <stdint.h>

#define NPIX  (512 * 512)
#define NB    8
#define NCH   32                 // fine-hist chunks per batch
#define CHPX  (NPIX / NCH)       // 8192 px per chunk (u16 cell counts can't overflow)
#define FB    128                // fine bins per axis (2 per coarse bin)
#define MPW   161                // padded mid row width: 16 guard + 128 + 17 guard
#define HDR_FLOATS 1024          // ws: [0,512) minmax, [512,520) mi, [520,561) counters

typedef __attribute__((ext_vector_type(4))) unsigned uint4v;
typedef __attribute__((ext_vector_type(4))) float    float4v;

// 33-tap Gaussian conv kernel, w[k] = exp(-(16-k)^2/8)  (sigma=1 bin, fine=1/2 bin)
__device__ constexpr float WK[33] = {
  1.2664166e-14f, 6.1019365e-13f, 2.2897490e-11f, 6.6915858e-10f,
  1.5229979e-08f, 2.6995785e-07f, 3.7266532e-06f, 4.0065297e-05f,
  3.3546263e-04f, 2.1874911e-03f, 1.1108997e-02f, 4.3936934e-02f,
  1.3533528e-01f, 3.2465247e-01f, 6.0653066e-01f, 8.8249690e-01f,
  1.0f,
  8.8249690e-01f, 6.0653066e-01f, 3.2465247e-01f, 1.3533528e-01f,
  4.3936934e-02f, 1.1108997e-02f, 2.1874911e-03f, 3.3546263e-04f,
  4.0065297e-05f, 3.7266532e-06f, 2.6995785e-07f, 1.5229979e-08f,
  6.6915858e-10f, 2.2897490e-11f, 6.1019365e-13f, 1.2664166e-14f
};

// ---- kernel 1: per-block min/max partials; re-arms all 41 counters ----
__global__ __launch_bounds__(1024) void minmax_kernel(const float* __restrict__ pred,
                                                      const float* __restrict__ tgt,
                                                      float2* __restrict__ mm,
                                                      unsigned* __restrict__ cnt) {
  __shared__ float smin[16], smax[16];
  const int tid = threadIdx.x, lane = tid & 63, wave = tid >> 6;
  if (blockIdx.x == 0 && tid < 41) cnt[tid] = 0u;   // re-armed every launch/replay
  const int pair = blockIdx.x >> 4, sub = blockIdx.x & 15;
  const float* src = pair < 8 ? pred + (size_t)pair * NPIX
                              : tgt  + (size_t)(pair - 8) * NPIX;
  const float4v* s4 = (const float4v*)src + sub * 4096;
  float vmin = 3.0e38f, vmax = -3.0e38f;
  #pragma unroll
  for (int k = 0; k < 4; ++k) {
    float4v v = s4[k * 1024 + tid];
    vmin = fminf(vmin, fminf(fminf(v[0], v[1]), fminf(v[2], v[3])));
    vmax = fmaxf(vmax, fmaxf(fmaxf(v[0], v[1]), fmaxf(v[2], v[3])));
  }
  #pragma unroll
  for (int off = 32; off; off >>= 1) {
    vmin = fminf(vmin, __shfl_xor(vmin, off));
    vmax = fmaxf(vmax, __shfl_xor(vmax, off));
  }
  if (lane == 0) { smin[wave] = vmin; smax[wave] = vmax; }
  __syncthreads();
  if (tid == 0) {
    float m = smin[0], M = smax[0];
    #pragma unroll
    for (int w = 1; w < 16; ++w) { m = fminf(m, smin[w]); M = fmaxf(M, smax[w]); }
    mm[blockIdx.x] = (float2){m, M};
  }
}

// ---- kernel 2 (fused): 256 blocks x 1024 thr.
// Phase H: fine hist (full chip, same per-CU load as the best 4-dispatch run).
// Merge tree via last-arriver (NO spins; non-last blocks exit; deadlock-
// impossible; fences tid0-only — R2 post-mortem):
//   level 1: 8 chunks -> merged[b][g] u32   (32 parallel blocks, 256KB read)
//   level 2: 4 groups -> fineF[b] f32       (8 parallel blocks, 256KB read)
// then the proven conv1/conv2/marginals/MI tail + final mean.
// Integer sums in any order are exact; counts < 2^24 -> f32 conversion exact
// -> bit-identical result. Counters self-reset + re-armed by minmax.
__global__ __launch_bounds__(1024) void hist_tail_kernel(const float* __restrict__ pred,
                                                         const float* __restrict__ tgt,
                                                         const float2* __restrict__ mm,
                                                         unsigned* __restrict__ part,
                                                         unsigned* __restrict__ merged,
                                                         float* __restrict__ fineF,
                                                         unsigned* __restrict__ cnt,
                                                         float* __restrict__ mi,
                                                         float* __restrict__ out) {
  __shared__ float S[14608];   // tail scratch; phase H aliases first 32KB as u32 H[8192]
  __shared__ unsigned s_last;
  unsigned* H = (unsigned*)S;
  const int tid = threadIdx.x, lane = tid & 63, wave = tid >> 6;
  const int blk = blockIdx.x, b = blk >> 5, c = blk & 31;

  // batch minmax from the 16 per-image partials
  float pmin = 3.0e38f, pmax = -3.0e38f, tmin = 3.0e38f, tmax = -3.0e38f;
  #pragma unroll
  for (int s2 = 0; s2 < 16; ++s2) {
    float2 a = mm[b * 16 + s2], d = mm[(8 + b) * 16 + s2];
    pmin = fminf(pmin, a.x); pmax = fmaxf(pmax, a.y);
    tmin = fminf(tmin, d.x); tmax = fmaxf(tmax, d.y);
  }
  const float sp = 126.0f / (pmax - pmin + 1e-10f), op = -pmin * sp + 0.5f;
  const float st = 126.0f / (tmax - tmin + 1e-10f), ot = -tmin * st + 0.5f;

  // ---- phase H: bank-swizzled LDS hist of chunk (b,c), u16-packed ----
  ((uint4v*)H)[tid]        = (uint4v){0u, 0u, 0u, 0u};
  ((uint4v*)H)[1024 + tid] = (uint4v){0u, 0u, 0u, 0u};
  __syncthreads();

  const float4v* p4 = (const float4v*)(pred + (size_t)b * NPIX + (size_t)c * CHPX);
  const float4v* t4 = (const float4v*)(tgt  + (size_t)b * NPIX + (size_t)c * CHPX);
  #pragma unroll
  for (int it = 0; it < 2; ++it) {
    float4v vp = p4[it * 1024 + tid];
    float4v vt = t4[it * 1024 + tid];
    #pragma unroll
    for (int j = 0; j < 4; ++j) {
      int fp = (int)(vp[j] * sp + op);      // 0..126
      int ft = (int)(vt[j] * st + ot);
      int w  = (fp << 6) | (ft >> 1);
      atomicAdd(&H[w ^ ((fp & 7) << 2)], 1u << ((ft & 1) << 4));  // bank-swizzled
    }
  }
  __syncthreads();

  // flush private partial (un-swizzled -> linear), plain coalesced stores
  {
    uint4v* dst = (uint4v*)(part + ((size_t)blk << 13));
    #pragma unroll
    for (int j = 0; j < 2; ++j) {
      int g = j * 1024 + tid;
      dst[g] = ((uint4v*)H)[g ^ ((g >> 4) & 7)];
    }
  }
  __syncthreads();                          // vmcnt(0) per wave: stores in L2
  const int g = c >> 3;
  if (tid == 0) {                           // tid0-only fences (R2 lesson)
    __threadfence();                        // release part[]
    unsigned old = atomicAdd(&cnt[(b << 2) | g], 1u);
    unsigned last = (old == 7u) ? 1u : 0u;
    if (last) { atomicExch(&cnt[(b << 2) | g], 0u); __threadfence(); }  // acquire
    s_last = last;
  }
  __syncthreads();
  if (!s_last) return;                      // non-last blocks exit (no spin)

  // ---- merge level 1: sum 8 chunk partials -> merged[b][g] (u32 cells) ----
  {
    const unsigned* src = part + ((size_t)(b * 32 + g * 8) << 13);
    unsigned* mg = merged + ((size_t)((b << 2) | g) << 14);
    #pragma unroll
    for (int k = 0; k < 8; ++k) {
      int w = k * 1024 + tid;               // word (fp<<6)|j -> cells 2w, 2w+1
      unsigned lo = 0, hi = 0;
      #pragma unroll
      for (int cc = 0; cc < 8; ++cc) {
        unsigned v = src[((size_t)cc << 13) + w];
        lo += v & 0xFFFFu; hi += v >> 16;
      }
      mg[2 * w]     = lo;
      mg[2 * w + 1] = hi;
    }
  }
  __syncthreads();                          // stores drained before release
  if (tid == 0) {
    __threadfence();                        // release merged[b][g]
    unsigned old = atomicAdd(&cnt[32 + b], 1u);
    unsigned last = (old == 3u) ? 1u : 0u;
    if (last) { atomicExch(&cnt[32 + b], 0u); __threadfence(); }  // acquire
    s_last = last;
  }
  __syncthreads();
  if (!s_last) return;

  // ---- merge level 2: sum 4 group partials -> fineF[b] (f32, exact) ----
  {
    const unsigned* m0 = merged + ((size_t)(b << 2) << 14);
    float* fo = fineF + (size_t)b * 16384;
    #pragma unroll
    for (int k = 0; k < 16; ++k) {
      int cell = k * 1024 + tid;
      unsigned s = m0[cell] + m0[(1 << 14) + cell]
                 + m0[(2 << 14) + cell] + m0[(3 << 14) + cell];
      fo[cell] = (float)s;                  // < 2^24: exact
    }
  }
  __syncthreads();                          // same-CU read-after-write (R4-proven)

  // ---- phase A: conv along fine-p rows, decimate x2 -> S[0,10304) ----
  const float* fineG = fineF + (size_t)b * 16384;   // f32 [128][128]
  {
    const int ft = tid & 127, r = tid >> 7;
    const float* fb = fineG + ft;
    float v[47];
    #pragma unroll
    for (int t = 0; t < 47; ++t) {
      int fp = 16 * r - 16 + t;
      v[t] = ((unsigned)fp < 128u) ? fb[fp << 7] : 0.0f;
    }
    float acc[8];
    #pragma unroll
    for (int d = 0; d < 8; ++d) {
      float a = 0.0f;
      #pragma unroll
      for (int k = 0; k < 33; ++k) a += WK[k] * v[2 * d + k];
      acc[d] = a;
    }
    #pragma unroll
    for (int d = 0; d < 8; ++d)
      S[(8 * r + d) * MPW + ft + 16] = acc[d];
    // zero guard columns: 64 rows x (16 left + 17 right)
    #pragma unroll
    for (int ii = 0; ii < 3; ++ii) {
      int idx = ii * 1024 + tid;
      if (idx < 64 * 33) {
        int rr = idx / 33, cc = idx % 33;
        int col = cc < 16 ? cc : cc + 128;
        S[rr * MPW + col] = 0.0f;
      }
    }
  }
  __syncthreads();

  // ---- phase B: conv along fine-t axis -> pxy ----
  const int i = tid & 63, js = (tid >> 6) << 2;
  {
    float v[39];
    #pragma unroll
    for (int t = 0; t < 39; ++t) v[t] = S[i * MPW + 2 * js + t];
    float acc[4] = {0.0f, 0.0f, 0.0f, 0.0f};
    #pragma unroll
    for (int d = 0; d < 4; ++d)
      #pragma unroll
      for (int k = 0; k < 33; ++k) acc[d] += WK[k] * v[2 * d + k];
    const float invN = 1.0f / (float)NPIX;
    #pragma unroll
    for (int d = 0; d < 4; ++d) S[10304 + i * 65 + js + d] = acc[d] * invN;
  }
  __syncthreads();

  // marginals: wave w owns 4 rows + 4 cols (16-lane groups)
  {
    const int l16 = lane & 15, sub16 = lane >> 4;
    int row = 4 * wave + sub16;
    float s = 0.0f;
    #pragma unroll
    for (int k = 0; k < 4; ++k) s += S[10304 + row * 65 + l16 * 4 + k];
    #pragma unroll
    for (int off = 8; off; off >>= 1) s += __shfl_xor(s, off);
    if (l16 == 0) S[14464 + row] = s;     // px
    float t2 = 0.0f;
    #pragma unroll
    for (int k = 0; k < 4; ++k) t2 += S[10304 + (l16 * 4 + k) * 65 + row];
    #pragma unroll
    for (int off = 8; off; off >>= 1) t2 += __shfl_xor(t2, off);
    if (l16 == 0) S[14528 + row] = t2;    // py
  }
  __syncthreads();

  float a = 0.0f;
  #pragma unroll
  for (int r = 0; r < 4; ++r) {
    int e = r * 1024 + tid;
    int ii = e >> 6, jj = e & 63;
    float pv = S[10304 + ii * 65 + jj];
    float d = S[14464 + ii] * S[14528 + jj] + 1e-10f;
    a += pv * __logf((pv + 1e-10f) / d);
  }
  #pragma unroll
  for (int off = 32; off; off >>= 1) a += __shfl_xor(a, off);
  if (lane == 0) S[14592 + wave] = a;
  __syncthreads();

  if (tid == 0) {
    float s = 0.0f;
    #pragma unroll
    for (int w = 0; w < 16; ++w) s += S[14592 + w];
    atomicExch(&mi[b], s);                 // device-scope store
    __threadfence();                       // tid0-only release
    unsigned prev = atomicAdd(&cnt[40], 1u);
    if (prev == NB - 1) {                  // last tail block finalizes
      __threadfence();                     // tid0-only acquire
      float tot = 0.0f;
      #pragma unroll
      for (int k = 0; k < NB; ++k) tot += atomicAdd(&mi[k], 0.0f);  // atomic read
      out[0] = -(tot * (1.0f / NB));
      atomicExch(&cnt[40], 0u);            // self-reset (solo-replay safety)
    }
  }
}

extern "C" void kernel_launch(void* const* d_in, const int* in_sizes, int n_in,
                              void* d_out, int out_size, void* d_ws, size_t ws_size,
                              hipStream_t stream) {
  const float* pred = (const float*)d_in[0];
  const float* tgt  = (const float*)d_in[1];
  float*    out  = (float*)d_out;
  float*    wsf  = (float*)d_ws;
  float2*   mm   = (float2*)d_ws;                      // 256 float2 in [0,512) floats
  float*    mi   = wsf + 512;                          // 8 floats
  unsigned* cnt  = (unsigned*)(wsf + 520);             // [0,32) lvl1, [32,40) lvl2, 40 final
  unsigned* part = (unsigned*)(wsf + HDR_FLOATS);      // 256*8192 words = 8MB
  unsigned* merged = part + ((size_t)256 << 13);       // 32*16384 words = 2MB
  float*    fineF  = (float*)(merged + ((size_t)32 << 14));   // 8*16384 f32 = 512KB

  minmax_kernel   <<<256, 1024, 0, stream>>>(pred, tgt, mm, cnt);
  hist_tail_kernel<<<256, 1024, 0, stream>>>(pred, tgt, mm, part, merged, fineF,
                                             cnt, mi, out);
}

// Round 6
// 37.307 us; speedup vs baseline: 1.2556x; 1.2556x over previous
//
#include <hip/hip_runtime.h>
#include <stdint.h>

#define NPIX  (512 * 512)
#define NB    8
#define NCH   32                 // fine-hist chunks per batch
#define CHPX  (NPIX / NCH)       // 8192 px per chunk (u16 cell counts can't overflow)
#define FB    128                // fine bins per axis (2 per coarse bin)
#define MPW   161                // padded mid row width: 16 guard + 128 + 17 guard
#define HDR_FLOATS 1024          // ws: [0,512) minmax, [512,520) mi, [520,537) counters

typedef __attribute__((ext_vector_type(4))) unsigned uint4v;
typedef __attribute__((ext_vector_type(4))) float    float4v;

// Agent-scope (device-coherent, per-instruction) memory ops: compile to
// global_load/store with sc0 sc1 — data moves via the LLC coherence point,
// NO buffer_wbl2 cache walks (the R2/R4/R5 fence catastrophe).
__device__ __forceinline__ unsigned agent_ldu(const unsigned* p) {
  return __hip_atomic_load(p, __ATOMIC_RELAXED, __HIP_MEMORY_SCOPE_AGENT);
}
__device__ __forceinline__ float agent_ldf(const float* p) {
  return __hip_atomic_load(p, __ATOMIC_RELAXED, __HIP_MEMORY_SCOPE_AGENT);
}
__device__ __forceinline__ void agent_stu(unsigned* p, unsigned v) {
  __hip_atomic_store(p, v, __ATOMIC_RELAXED, __HIP_MEMORY_SCOPE_AGENT);
}
__device__ __forceinline__ void agent_stf(float* p, float v) {
  __hip_atomic_store(p, v, __ATOMIC_RELAXED, __HIP_MEMORY_SCOPE_AGENT);
}

// 33-tap Gaussian conv kernel, w[k] = exp(-(16-k)^2/8)  (sigma=1 bin, fine=1/2 bin)
__device__ constexpr float WK[33] = {
  1.2664166e-14f, 6.1019365e-13f, 2.2897490e-11f, 6.6915858e-10f,
  1.5229979e-08f, 2.6995785e-07f, 3.7266532e-06f, 4.0065297e-05f,
  3.3546263e-04f, 2.1874911e-03f, 1.1108997e-02f, 4.3936934e-02f,
  1.3533528e-01f, 3.2465247e-01f, 6.0653066e-01f, 8.8249690e-01f,
  1.0f,
  8.8249690e-01f, 6.0653066e-01f, 3.2465247e-01f, 1.3533528e-01f,
  4.3936934e-02f, 1.1108997e-02f, 2.1874911e-03f, 3.3546263e-04f,
  4.0065297e-05f, 3.7266532e-06f, 2.6995785e-07f, 1.5229979e-08f,
  6.6915858e-10f, 2.2897490e-11f, 6.1019365e-13f, 1.2664166e-14f
};

// ---- kernel 1: per-block min/max partials; re-arms all 17 counters ----
__global__ __launch_bounds__(1024) void minmax_kernel(const float* __restrict__ pred,
                                                      const float* __restrict__ tgt,
                                                      float2* __restrict__ mm,
                                                      unsigned* __restrict__ cnt) {
  __shared__ float smin[16], smax[16];
  const int tid = threadIdx.x, lane = tid & 63, wave = tid >> 6;
  if (blockIdx.x == 0 && tid < 17) cnt[tid] = 0u;   // re-armed every launch/replay
  const int pair = blockIdx.x >> 4, sub = blockIdx.x & 15;
  const float* src = pair < 8 ? pred + (size_t)pair * NPIX
                              : tgt  + (size_t)(pair - 8) * NPIX;
  const float4v* s4 = (const float4v*)src + sub * 4096;
  float vmin = 3.0e38f, vmax = -3.0e38f;
  #pragma unroll
  for (int k = 0; k < 4; ++k) {
    float4v v = s4[k * 1024 + tid];
    vmin = fminf(vmin, fminf(fminf(v[0], v[1]), fminf(v[2], v[3])));
    vmax = fmaxf(vmax, fmaxf(fmaxf(v[0], v[1]), fmaxf(v[2], v[3])));
  }
  #pragma unroll
  for (int off = 32; off; off >>= 1) {
    vmin = fminf(vmin, __shfl_xor(vmin, off));
    vmax = fmaxf(vmax, __shfl_xor(vmax, off));
  }
  if (lane == 0) { smin[wave] = vmin; smax[wave] = vmax; }
  __syncthreads();
  if (tid == 0) {
    float m = smin[0], M = smax[0];
    #pragma unroll
    for (int w = 1; w < 16; ++w) { m = fminf(m, smin[w]); M = fmaxf(M, smax[w]); }
    mm[blockIdx.x] = (float2){m, M};
  }
}

// ---- kernel 2 (fused, fence-free): 256 blocks x 1024 thr.
// Phase H: fine hist (full chip) -> agent-store private partial.
// Sync A: tid0 arrival atomicAdd + tid0 spin (s_sleep poll) for 32 siblings
//         — NO __threadfence (agent-scope stores are already at the LLC after
//         __syncthreads' vmcnt(0) drain; agent loads bypass stale L1/L2).
// Phase R: all 32 blocks of batch b cooperatively reduce (one 256-word slice
//          each, integer-exact), agent-store fineF.
// Sync B: arrival; c!=0 exit; c==0 spins, then runs the proven conv/MI tail.
// Deadlock-impossible: 256 blocks <= chip capacity (16 waves, 57KB LDS,
// ~52 VGPR -> >=1 block/CU), CP dispatches greedily. Counters re-armed by
// minmax each launch; every word of part/fineF is overwritten each launch
// (poison-safe). Integer sums + exact f32 conversion -> bit-identical result.
__global__ __launch_bounds__(1024) void fused_kernel(const float* __restrict__ pred,
                                                     const float* __restrict__ tgt,
                                                     const float2* __restrict__ mm,
                                                     unsigned* __restrict__ part,
                                                     float* __restrict__ fineF,
                                                     unsigned* __restrict__ cnt,
                                                     float* __restrict__ mi,
                                                     float* __restrict__ out) {
  __shared__ float S[14608];   // tail scratch; phases H/R alias it as u32 H[]
  unsigned* H = (unsigned*)S;
  const int tid = threadIdx.x, lane = tid & 63, wave = tid >> 6;
  const int blk = blockIdx.x, b = blk >> 5, c = blk & 31;

  // batch minmax from the 16 per-image partials
  float pmin = 3.0e38f, pmax = -3.0e38f, tmin = 3.0e38f, tmax = -3.0e38f;
  #pragma unroll
  for (int s2 = 0; s2 < 16; ++s2) {
    float2 a = mm[b * 16 + s2], d = mm[(8 + b) * 16 + s2];
    pmin = fminf(pmin, a.x); pmax = fmaxf(pmax, a.y);
    tmin = fminf(tmin, d.x); tmax = fmaxf(tmax, d.y);
  }
  const float sp = 126.0f / (pmax - pmin + 1e-10f), op = -pmin * sp + 0.5f;
  const float st = 126.0f / (tmax - tmin + 1e-10f), ot = -tmin * st + 0.5f;

  // ---- phase H: bank-swizzled LDS hist of chunk (b,c), u16-packed ----
  ((uint4v*)H)[tid]        = (uint4v){0u, 0u, 0u, 0u};
  ((uint4v*)H)[1024 + tid] = (uint4v){0u, 0u, 0u, 0u};
  __syncthreads();

  const float4v* p4 = (const float4v*)(pred + (size_t)b * NPIX + (size_t)c * CHPX);
  const float4v* t4 = (const float4v*)(tgt  + (size_t)b * NPIX + (size_t)c * CHPX);
  #pragma unroll
  for (int it = 0; it < 2; ++it) {
    float4v vp = p4[it * 1024 + tid];
    float4v vt = t4[it * 1024 + tid];
    #pragma unroll
    for (int j = 0; j < 4; ++j) {
      int fp = (int)(vp[j] * sp + op);      // 0..126
      int ft = (int)(vt[j] * st + ot);
      int w  = (fp << 6) | (ft >> 1);
      atomicAdd(&H[w ^ ((fp & 7) << 2)], 1u << ((ft & 1) << 4));  // bank-swizzled
    }
  }
  __syncthreads();

  // flush private partial with agent-scope stores (un-swizzled -> linear).
  // Per-dword un-swizzle w ^ (((w>>6)&7)<<2) == the uint4-level XOR of R1;
  // (w>>6) is wave-constant for w = j*1024+tid -> LDS reads stay conflict-free.
  {
    unsigned* dst = part + ((size_t)blk << 13);
    #pragma unroll
    for (int j = 0; j < 8; ++j) {
      int w = j * 1024 + tid;
      agent_stu(dst + w, H[w ^ (((w >> 6) & 7) << 2)]);
    }
  }
  __syncthreads();                          // vmcnt(0)/wave: stores at LLC
  // ---- sync A: arrival + spin (tid0 only; no fences) ----
  if (tid == 0) {
    atomicAdd(&cnt[b], 1u);
    while (__hip_atomic_load(&cnt[b], __ATOMIC_RELAXED, __HIP_MEMORY_SCOPE_AGENT) < NCH)
      __builtin_amdgcn_s_sleep(2);
  }
  __syncthreads();

  // ---- phase R: reduce slice c of batch b (32 chunks, integer-exact) ----
  {
    const int wl = tid & 255, q = tid >> 8;      // 4 groups x 8 chunks
    const unsigned* srcB = part + ((size_t)b << 18);
    const int word = (c << 8) | wl;
    unsigned lo = 0, hi = 0;
    #pragma unroll
    for (int k = 0; k < 8; ++k) {
      unsigned v = agent_ldu(srcB + (((size_t)(q * 8 + k)) << 13) + word);
      lo += v & 0xFFFFu; hi += v >> 16;
    }
    H[(q << 8) | wl]          = lo;
    H[1024 + ((q << 8) | wl)] = hi;
  }
  __syncthreads();
  if (tid < 256) {
    unsigned lo = 0, hi = 0;
    #pragma unroll
    for (int q = 0; q < 4; ++q) {
      lo += H[(q << 8) | tid];
      hi += H[1024 + ((q << 8) | tid)];
    }
    const int word = (c << 8) | tid;             // cells 2*word, 2*word+1
    float* fo = fineF + ((size_t)b << 14) + (word << 1);
    agent_stf(fo,     (float)lo);                // counts < 2^24: exact
    agent_stf(fo + 1, (float)hi);
  }
  __syncthreads();                          // fineF stores at LLC
  // ---- sync B: arrival; only c==0 continues ----
  if (tid == 0) atomicAdd(&cnt[8 + b], 1u);
  if (c != 0) return;
  if (tid == 0) {
    while (__hip_atomic_load(&cnt[8 + b], __ATOMIC_RELAXED, __HIP_MEMORY_SCOPE_AGENT) < NCH)
      __builtin_amdgcn_s_sleep(2);
  }
  __syncthreads();

  // ---- phase A: conv along fine-p rows, decimate x2 -> S[0,10304) ----
  const float* fineG = fineF + ((size_t)b << 14);   // f32 [128][128]
  {
    const int ft = tid & 127, r = tid >> 7;
    const float* fb = fineG + ft;
    float v[47];
    #pragma unroll
    for (int t = 0; t < 47; ++t) {
      int fp = 16 * r - 16 + t;
      v[t] = ((unsigned)fp < 128u) ? agent_ldf(fb + (fp << 7)) : 0.0f;
    }
    float acc[8];
    #pragma unroll
    for (int d = 0; d < 8; ++d) {
      float a = 0.0f;
      #pragma unroll
      for (int k = 0; k < 33; ++k) a += WK[k] * v[2 * d + k];
      acc[d] = a;
    }
    #pragma unroll
    for (int d = 0; d < 8; ++d)
      S[(8 * r + d) * MPW + ft + 16] = acc[d];
    // zero guard columns: 64 rows x (16 left + 17 right)
    #pragma unroll
    for (int ii = 0; ii < 3; ++ii) {
      int idx = ii * 1024 + tid;
      if (idx < 64 * 33) {
        int rr = idx / 33, cc = idx % 33;
        int col = cc < 16 ? cc : cc + 128;
        S[rr * MPW + col] = 0.0f;
      }
    }
  }
  __syncthreads();

  // ---- phase B: conv along fine-t axis -> pxy ----
  const int i = tid & 63, js = (tid >> 6) << 2;
  {
    float v[39];
    #pragma unroll
    for (int t = 0; t < 39; ++t) v[t] = S[i * MPW + 2 * js + t];
    float acc[4] = {0.0f, 0.0f, 0.0f, 0.0f};
    #pragma unroll
    for (int d = 0; d < 4; ++d)
      #pragma unroll
      for (int k = 0; k < 33; ++k) acc[d] += WK[k] * v[2 * d + k];
    const float invN = 1.0f / (float)NPIX;
    #pragma unroll
    for (int d = 0; d < 4; ++d) S[10304 + i * 65 + js + d] = acc[d] * invN;
  }
  __syncthreads();

  // marginals: wave w owns 4 rows + 4 cols (16-lane groups)
  {
    const int l16 = lane & 15, sub16 = lane >> 4;
    int row = 4 * wave + sub16;
    float s = 0.0f;
    #pragma unroll
    for (int k = 0; k < 4; ++k) s += S[10304 + row * 65 + l16 * 4 + k];
    #pragma unroll
    for (int off = 8; off; off >>= 1) s += __shfl_xor(s, off);
    if (l16 == 0) S[14464 + row] = s;     // px
    float t2 = 0.0f;
    #pragma unroll
    for (int k = 0; k < 4; ++k) t2 += S[10304 + (l16 * 4 + k) * 65 + row];
    #pragma unroll
    for (int off = 8; off; off >>= 1) t2 += __shfl_xor(t2, off);
    if (l16 == 0) S[14528 + row] = t2;    // py
  }
  __syncthreads();

  float a = 0.0f;
  #pragma unroll
  for (int r = 0; r < 4; ++r) {
    int e = r * 1024 + tid;
    int ii = e >> 6, jj = e & 63;
    float pv = S[10304 + ii * 65 + jj];
    float d = S[14464 + ii] * S[14528 + jj] + 1e-10f;
    a += pv * __logf((pv + 1e-10f) / d);
  }
  #pragma unroll
  for (int off = 32; off; off >>= 1) a += __shfl_xor(a, off);
  if (lane == 0) S[14592 + wave] = a;
  __syncthreads();

  if (tid == 0) {
    float s = 0.0f;
    #pragma unroll
    for (int w = 0; w < 16; ++w) s += S[14592 + w];
    agent_stf(&mi[b], s);                           // coherent store (LLC)
    asm volatile("s_waitcnt vmcnt(0)" ::: "memory"); // store done before arrival
    unsigned prev = atomicAdd(&cnt[16], 1u);
    if (prev == NB - 1) {                           // last tail block finalizes
      float tot = 0.0f;
      #pragma unroll
      for (int k = 0; k < NB; ++k) tot += agent_ldf(&mi[k]);
      out[0] = -(tot * (1.0f / NB));
    }
  }
}

extern "C" void kernel_launch(void* const* d_in, const int* in_sizes, int n_in,
                              void* d_out, int out_size, void* d_ws, size_t ws_size,
                              hipStream_t stream) {
  const float* pred = (const float*)d_in[0];
  const float* tgt  = (const float*)d_in[1];
  float*    out  = (float*)d_out;
  float*    wsf  = (float*)d_ws;
  float2*   mm   = (float2*)d_ws;                      // 256 float2 in [0,512) floats
  float*    mi   = wsf + 512;                          // 8 floats
  unsigned* cnt  = (unsigned*)(wsf + 520);             // [0,8) hist, [8,16) reduce, 16 final
  unsigned* part = (unsigned*)(wsf + HDR_FLOATS);      // 256*8192 words = 8MB
  float*    fineF = (float*)(part + ((size_t)256 << 13));   // 8*16384 f32 = 512KB

  minmax_kernel<<<256, 1024, 0, stream>>>(pred, tgt, mm, cnt);
  fused_kernel <<<256, 1024, 0, stream>>>(pred, tgt, mm, part, fineF, cnt, mi, out);
}

// Round 7
// 30.529 us; speedup vs baseline: 1.5344x; 1.2220x over previous
//
#include <hip/hip_runtime.h>
#include <stdint.h>

#define NPIX  (512 * 512)
#define NB    8
#define NCH   32                 // fine-hist chunks per batch
#define CHPX  (NPIX / NCH)       // 8192 px per chunk (u16 cell counts can't overflow)
#define FB    128                // fine bins per axis (2 per coarse bin)
#define MPW   161                // padded mid row width: 16 guard + 128 + 17 guard
#define HDR_FLOATS 1024          // ws: [0,512) minmax, [512,520) mi, 520 cnt

typedef __attribute__((ext_vector_type(4))) unsigned uint4v;
typedef __attribute__((ext_vector_type(4))) float    float4v;

// 33-tap Gaussian conv kernel, w[k] = exp(-(16-k)^2/8)  (sigma=1 bin, fine=1/2 bin)
__device__ constexpr float WK[33] = {
  1.2664166e-14f, 6.1019365e-13f, 2.2897490e-11f, 6.6915858e-10f,
  1.5229979e-08f, 2.6995785e-07f, 3.7266532e-06f, 4.0065297e-05f,
  3.3546263e-04f, 2.1874911e-03f, 1.1108997e-02f, 4.3936934e-02f,
  1.3533528e-01f, 3.2465247e-01f, 6.0653066e-01f, 8.8249690e-01f,
  1.0f,
  8.8249690e-01f, 6.0653066e-01f, 3.2465247e-01f, 1.3533528e-01f,
  4.3936934e-02f, 1.1108997e-02f, 2.1874911e-03f, 3.3546263e-04f,
  4.0065297e-05f, 3.7266532e-06f, 2.6995785e-07f, 1.5229979e-08f,
  6.6915858e-10f, 2.2897490e-11f, 6.1019365e-13f, 1.2664166e-14f
};

// ---- kernel 1: per-block min/max partials; re-arms the tail counter ----
__global__ __launch_bounds__(1024) void minmax_kernel(const float* __restrict__ pred,
                                                      const float* __restrict__ tgt,
                                                      float2* __restrict__ mm,
                                                      unsigned* __restrict__ cnt) {
  __shared__ float smin[16], smax[16];
  const int tid = threadIdx.x, lane = tid & 63, wave = tid >> 6;
  if (blockIdx.x == 0 && tid < 4) cnt[tid] = 0u;    // re-armed every launch/replay
  const int pair = blockIdx.x >> 4, sub = blockIdx.x & 15;
  const float* src = pair < 8 ? pred + (size_t)pair * NPIX
                              : tgt  + (size_t)(pair - 8) * NPIX;
  const float4v* s4 = (const float4v*)src + sub * 4096;
  float vmin = 3.0e38f, vmax = -3.0e38f;
  #pragma unroll
  for (int k = 0; k < 4; ++k) {
    float4v v = s4[k * 1024 + tid];
    vmin = fminf(vmin, fminf(fminf(v[0], v[1]), fminf(v[2], v[3])));
    vmax = fmaxf(vmax, fmaxf(fmaxf(v[0], v[1]), fmaxf(v[2], v[3])));
  }
  #pragma unroll
  for (int off = 32; off; off >>= 1) {
    vmin = fminf(vmin, __shfl_xor(vmin, off));
    vmax = fmaxf(vmax, __shfl_xor(vmax, off));
  }
  if (lane == 0) { smin[wave] = vmin; smax[wave] = vmax; }
  __syncthreads();
  if (tid == 0) {
    float m = smin[0], M = smax[0];
    #pragma unroll
    for (int w = 1; w < 16; ++w) { m = fminf(m, smin[w]); M = fmaxf(M, smax[w]); }
    mm[blockIdx.x] = (float2){m, M};
  }
}

// ---- kernel 2: 2D fine histogram (128x128) per (batch, chunk) ----
// NB*NCH = 256 blocks x 512 thr. LDS: 8192 u32 words, 2 u16 cells per word.
// Bank-swizzled cell addressing (w ^= (fp&7)<<2); flush un-permutes, so the
// global layout stays linear.
__global__ __launch_bounds__(512) void fine_hist_kernel(const float* __restrict__ pred,
                                                        const float* __restrict__ tgt,
                                                        const float2* __restrict__ mm,
                                                        unsigned* __restrict__ part) {
  __shared__ unsigned H[FB * FB / 2];   // 32KB
  const int tid = threadIdx.x;
  const int b = blockIdx.x >> 5, c = blockIdx.x & 31;

  float pmin = 3.0e38f, pmax = -3.0e38f, tmin = 3.0e38f, tmax = -3.0e38f;
  #pragma unroll
  for (int s2 = 0; s2 < 16; ++s2) {
    float2 a = mm[b * 16 + s2], d = mm[(8 + b) * 16 + s2];
    pmin = fminf(pmin, a.x); pmax = fmaxf(pmax, a.y);
    tmin = fminf(tmin, d.x); tmax = fmaxf(tmax, d.y);
  }
  // fine index f = round(t*2), t = 63*(x-min)/(range+eps):  f = x*sp + op
  const float sp = 126.0f / (pmax - pmin + 1e-10f), op = -pmin * sp + 0.5f;
  const float st = 126.0f / (tmax - tmin + 1e-10f), ot = -tmin * st + 0.5f;

  #pragma unroll
  for (int j = 0; j < 4; ++j)
    ((uint4v*)H)[j * 512 + tid] = (uint4v){0u, 0u, 0u, 0u};
  __syncthreads();

  const float4v* p4 = (const float4v*)(pred + (size_t)b * NPIX + (size_t)c * CHPX);
  const float4v* t4 = (const float4v*)(tgt  + (size_t)b * NPIX + (size_t)c * CHPX);
  #pragma unroll
  for (int it = 0; it < 4; ++it) {
    float4v vp = p4[it * 512 + tid];
    float4v vt = t4[it * 512 + tid];
    #pragma unroll
    for (int j = 0; j < 4; ++j) {
      int fp = (int)(vp[j] * sp + op);      // 0..126
      int ft = (int)(vt[j] * st + ot);
      int w  = (fp << 6) | (ft >> 1);
      atomicAdd(&H[w ^ ((fp & 7) << 2)], 1u << ((ft & 1) << 4));
    }
  }
  __syncthreads();

  uint4v* dst = (uint4v*)(part + ((size_t)blockIdx.x << 13));
  #pragma unroll
  for (int j = 0; j < 4; ++j) {
    int g = j * 512 + tid;                  // uint4 index; word base = 4g
    dst[g] = ((uint4v*)H)[g ^ ((g >> 4) & 7)];   // un-swizzle (wave-const XOR)
  }
}

// ---- kernel 3: sum 32 chunk partials -> f32 fine histogram [128][128] ----
// Vectorized: 64 blocks x 256 thr; thread sums 32 chunks of one uint4
// (16B/lane coalesced, 4x fewer VMEM ops than the scalar version),
// writes 8 floats as two float4. Integer adds: order-free, exact.
__global__ __launch_bounds__(256) void reduce_fine_kernel(const unsigned* __restrict__ part,
                                                          float* __restrict__ fineF) {
  const int tid = threadIdx.x;
  const int b = blockIdx.x >> 3, s = blockIdx.x & 7;
  const int idx4 = s * 256 + tid;                     // uint4 index in [0, 2048)
  const uint4v* src = (const uint4v*)part + ((size_t)b << 16) / 4 + idx4;
  unsigned lo[4] = {0u, 0u, 0u, 0u}, hi[4] = {0u, 0u, 0u, 0u};
  #pragma unroll 8
  for (int c = 0; c < 32; ++c) {
    uint4v v = src[(size_t)c * 2048];
    #pragma unroll
    for (int k = 0; k < 4; ++k) { lo[k] += v[k] & 0xFFFFu; hi[k] += v[k] >> 16; }
  }
  float4v o0, o1;                                     // words 4*idx4 .. 4*idx4+3
  o0[0] = (float)lo[0]; o0[1] = (float)hi[0];         // counts < 2^24: exact
  o0[2] = (float)lo[1]; o0[3] = (float)hi[1];
  o1[0] = (float)lo[2]; o1[1] = (float)hi[2];
  o1[2] = (float)lo[3]; o1[3] = (float)hi[3];
  float4v* dst = (float4v*)(fineF + (size_t)b * 16384) + idx4 * 2;
  dst[0] = o0; dst[1] = o1;
}

// ---- kernel 4 (fused tail): conv1 (fine-p axis, decimate x2) -> mid in LDS ->
//      conv2 (fine-t axis) -> marginals -> MI -> last-block final mean ----
__global__ __launch_bounds__(1024) void tail_kernel(const float* __restrict__ fineF,
                                                    float* __restrict__ mi,
                                                    unsigned* __restrict__ cnt,
                                                    float* __restrict__ out) {
  __shared__ float S[14608];   // [0,10304) mid[64][161] | [10304,14464) pxy[64][65]
                               // | 14464 px | 14528 py | 14592 wred
  const int tid = threadIdx.x, lane = tid & 63, wave = tid >> 6;
  const int b = blockIdx.x;

  // ---- phase A: conv along fine-p rows, decimate x2 -> S[0,10304) ----
  {
    const int ft = tid & 127, r = tid >> 7;
    const float* fb = fineF + ((size_t)b << 14) + ft;
    float v[47];
    #pragma unroll
    for (int t = 0; t < 47; ++t) {
      int fp = 16 * r - 16 + t;
      v[t] = ((unsigned)fp < 128u) ? fb[fp << 7] : 0.0f;
    }
    float acc[8];
    #pragma unroll
    for (int d = 0; d < 8; ++d) {
      float a = 0.0f;
      #pragma unroll
      for (int k = 0; k < 33; ++k) a += WK[k] * v[2 * d + k];
      acc[d] = a;
    }
    #pragma unroll
    for (int d = 0; d < 8; ++d)
      S[(8 * r + d) * MPW + ft + 16] = acc[d];
    // zero guard columns: 64 rows x (16 left + 17 right)
    #pragma unroll
    for (int ii = 0; ii < 3; ++ii) {
      int idx = ii * 1024 + tid;
      if (idx < 64 * 33) {
        int rr = idx / 33, cc = idx % 33;
        int col = cc < 16 ? cc : cc + 128;
        S[rr * MPW + col] = 0.0f;
      }
    }
  }
  __syncthreads();

  // ---- phase B: conv along fine-t axis -> pxy ----
  const int i = tid & 63, js = (tid >> 6) << 2;
  {
    float v[39];
    #pragma unroll
    for (int t = 0; t < 39; ++t) v[t] = S[i * MPW + 2 * js + t];
    float acc[4] = {0.0f, 0.0f, 0.0f, 0.0f};
    #pragma unroll
    for (int d = 0; d < 4; ++d)
      #pragma unroll
      for (int k = 0; k < 33; ++k) acc[d] += WK[k] * v[2 * d + k];
    const float invN = 1.0f / (float)NPIX;
    #pragma unroll
    for (int d = 0; d < 4; ++d) S[10304 + i * 65 + js + d] = acc[d] * invN;
  }
  __syncthreads();

  // marginals: wave w owns 4 rows + 4 cols (16-lane groups)
  {
    const int l16 = lane & 15, sub16 = lane >> 4;
    int row = 4 * wave + sub16;
    float s = 0.0f;
    #pragma unroll
    for (int k = 0; k < 4; ++k) s += S[10304 + row * 65 + l16 * 4 + k];
    #pragma unroll
    for (int off = 8; off; off >>= 1) s += __shfl_xor(s, off);
    if (l16 == 0) S[14464 + row] = s;     // px
    float t2 = 0.0f;
    #pragma unroll
    for (int k = 0; k < 4; ++k) t2 += S[10304 + (l16 * 4 + k) * 65 + row];
    #pragma unroll
    for (int off = 8; off; off >>= 1) t2 += __shfl_xor(t2, off);
    if (l16 == 0) S[14528 + row] = t2;    // py
  }
  __syncthreads();

  float a = 0.0f;
  #pragma unroll
  for (int r = 0; r < 4; ++r) {
    int e = r * 1024 + tid;
    int ii = e >> 6, jj = e & 63;
    float pv = S[10304 + ii * 65 + jj];
    float d = S[14464 + ii] * S[14528 + jj] + 1e-10f;
    a += pv * __logf((pv + 1e-10f) / d);
  }
  #pragma unroll
  for (int off = 32; off; off >>= 1) a += __shfl_xor(a, off);
  if (lane == 0) S[14592 + wave] = a;
  __syncthreads();

  if (tid == 0) {
    float s = 0.0f;
    #pragma unroll
    for (int w = 0; w < 16; ++w) s += S[14592 + w];
    atomicExch(&mi[b], s);                 // device-scope atomic store
    __threadfence();                       // release: mi visible before counter
    unsigned prev = atomicAdd(cnt, 1u);
    if (prev == NB - 1) {                  // last block finalizes
      __threadfence();                     // acquire
      float tot = 0.0f;
      #pragma unroll
      for (int k = 0; k < NB; ++k) tot += atomicAdd(&mi[k], 0.0f);  // atomic read
      out[0] = -(tot * (1.0f / NB));
      atomicExch(cnt, 0u);                 // self-reset (replay safety)
    }
  }
}

extern "C" void kernel_launch(void* const* d_in, const int* in_sizes, int n_in,
                              void* d_out, int out_size, void* d_ws, size_t ws_size,
                              hipStream_t stream) {
  const float* pred = (const float*)d_in[0];
  const float* tgt  = (const float*)d_in[1];
  float*    out  = (float*)d_out;
  float*    wsf  = (float*)d_ws;
  float2*   mm   = (float2*)d_ws;                      // 256 float2 in [0,512) floats
  float*    mi   = wsf + 512;                          // 8 floats
  unsigned* cnt  = (unsigned*)(wsf + 520);             // tail completion counter
  unsigned* part = (unsigned*)(wsf + HDR_FLOATS);      // NB*NCH*8192 words = 8MB
  float*    fineF = wsf + HDR_FLOATS + (size_t)NB * NCH * 8192;   // NB*16384 f32

  minmax_kernel     <<<256,      1024, 0, stream>>>(pred, tgt, mm, cnt);
  fine_hist_kernel  <<<NB * NCH,  512, 0, stream>>>(pred, tgt, mm, part);
  reduce_fine_kernel<<<NB * 8,    256, 0, stream>>>(part, fineF);
  tail_kernel       <<<NB,       1024, 0, stream>>>(fineF, mi, cnt, out);
}

// Round 8
// 29.758 us; speedup vs baseline: 1.5741x; 1.0259x over previous
//
#include <hip/hip_runtime.h>
#include <stdint.h>

#define NPIX  (512 * 512)
#define NB    8
#define NCH   32                 // fine-hist chunks per batch
#define CHPX  (NPIX / NCH)       // 8192 px per chunk (u16 cell counts can't overflow)
#define FB    128                // fine bins per axis (2 per coarse bin)
#define MPW   161                // padded mid row width: 16 guard + 128 + 17 guard
#define HDR_FLOATS 1024          // ws: [0,512) minmax partials, [512,520) mi, 520 cnt

typedef __attribute__((ext_vector_type(4))) unsigned uint4v;
typedef __attribute__((ext_vector_type(4))) float    float4v;

// 33-tap Gaussian conv kernel, w[k] = exp(-(16-k)^2/8)  (sigma=1 bin, fine=1/2 bin)
__device__ constexpr float WK[33] = {
  1.2664166e-14f, 6.1019365e-13f, 2.2897490e-11f, 6.6915858e-10f,
  1.5229979e-08f, 2.6995785e-07f, 3.7266532e-06f, 4.0065297e-05f,
  3.3546263e-04f, 2.1874911e-03f, 1.1108997e-02f, 4.3936934e-02f,
  1.3533528e-01f, 3.2465247e-01f, 6.0653066e-01f, 8.8249690e-01f,
  1.0f,
  8.8249690e-01f, 6.0653066e-01f, 3.2465247e-01f, 1.3533528e-01f,
  4.3936934e-02f, 1.1108997e-02f, 2.1874911e-03f, 3.3546263e-04f,
  4.0065297e-05f, 3.7266532e-06f, 2.6995785e-07f, 1.5229979e-08f,
  6.6915858e-10f, 2.2897490e-11f, 6.1019365e-13f, 1.2664166e-14f
};

// ---- kernel 1: per-block min/max partials; re-arms the tail counter ----
__global__ __launch_bounds__(1024) void minmax_kernel(const float* __restrict__ pred,
                                                      const float* __restrict__ tgt,
                                                      float2* __restrict__ mm,
                                                      unsigned* __restrict__ cnt) {
  __shared__ float smin[16], smax[16];
  const int tid = threadIdx.x, lane = tid & 63, wave = tid >> 6;
  if (blockIdx.x == 0 && tid < 4) cnt[tid] = 0u;    // re-armed every launch/replay
  const int pair = blockIdx.x >> 4, sub = blockIdx.x & 15;
  const float* src = pair < 8 ? pred + (size_t)pair * NPIX
                              : tgt  + (size_t)(pair - 8) * NPIX;
  const float4v* s4 = (const float4v*)src + sub * 4096;
  float vmin = 3.0e38f, vmax = -3.0e38f;
  #pragma unroll
  for (int k = 0; k < 4; ++k) {
    float4v v = s4[k * 1024 + tid];
    vmin = fminf(vmin, fminf(fminf(v[0], v[1]), fminf(v[2], v[3])));
    vmax = fmaxf(vmax, fmaxf(fmaxf(v[0], v[1]), fmaxf(v[2], v[3])));
  }
  #pragma unroll
  for (int off = 32; off; off >>= 1) {
    vmin = fminf(vmin, __shfl_xor(vmin, off));
    vmax = fmaxf(vmax, __shfl_xor(vmax, off));
  }
  if (lane == 0) { smin[wave] = vmin; smax[wave] = vmax; }
  __syncthreads();
  if (tid == 0) {
    float m = smin[0], M = smax[0];
    #pragma unroll
    for (int w = 1; w < 16; ++w) { m = fminf(m, smin[w]); M = fmaxf(M, smax[w]); }
    mm[blockIdx.x] = (float2){m, M};
  }
}

// ---- kernel 2: 2D fine histogram (128x128) per (batch, chunk) ----
// NB*NCH = 256 blocks x 1024 thr (16 waves/CU: 2x the resident waves of the
// 512-thr version for VMEM/LDS-atomic latency hiding; same per-block work).
// LDS: 8192 u32 words, 2 u16 cells per word, bank-swizzled (w ^= (fp&7)<<2);
// flush un-permutes so the global layout stays linear.
__global__ __launch_bounds__(1024) void fine_hist_kernel(const float* __restrict__ pred,
                                                         const float* __restrict__ tgt,
                                                         const float2* __restrict__ mm,
                                                         unsigned* __restrict__ part) {
  __shared__ unsigned H[FB * FB / 2];   // 32KB
  const int tid = threadIdx.x;
  const int b = blockIdx.x >> 5, c = blockIdx.x & 31;

  float pmin = 3.0e38f, pmax = -3.0e38f, tmin = 3.0e38f, tmax = -3.0e38f;
  #pragma unroll
  for (int s2 = 0; s2 < 16; ++s2) {
    float2 a = mm[b * 16 + s2], d = mm[(8 + b) * 16 + s2];
    pmin = fminf(pmin, a.x); pmax = fmaxf(pmax, a.y);
    tmin = fminf(tmin, d.x); tmax = fmaxf(tmax, d.y);
  }
  // fine index f = round(t*2), t = 63*(x-min)/(range+eps):  f = x*sp + op
  const float sp = 126.0f / (pmax - pmin + 1e-10f), op = -pmin * sp + 0.5f;
  const float st = 126.0f / (tmax - tmin + 1e-10f), ot = -tmin * st + 0.5f;

  #pragma unroll
  for (int j = 0; j < 2; ++j)
    ((uint4v*)H)[j * 1024 + tid] = (uint4v){0u, 0u, 0u, 0u};
  __syncthreads();

  const float4v* p4 = (const float4v*)(pred + (size_t)b * NPIX + (size_t)c * CHPX);
  const float4v* t4 = (const float4v*)(tgt  + (size_t)b * NPIX + (size_t)c * CHPX);
  #pragma unroll
  for (int it = 0; it < 2; ++it) {
    float4v vp = p4[it * 1024 + tid];
    float4v vt = t4[it * 1024 + tid];
    #pragma unroll
    for (int j = 0; j < 4; ++j) {
      int fp = (int)(vp[j] * sp + op);      // 0..126
      int ft = (int)(vt[j] * st + ot);
      int w  = (fp << 6) | (ft >> 1);
      atomicAdd(&H[w ^ ((fp & 7) << 2)], 1u << ((ft & 1) << 4));
    }
  }
  __syncthreads();

  uint4v* dst = (uint4v*)(part + ((size_t)blockIdx.x << 13));
  #pragma unroll
  for (int j = 0; j < 2; ++j) {
    int g = j * 1024 + tid;                 // uint4 index; word base = 4g
    dst[g] = ((uint4v*)H)[g ^ ((g >> 4) & 7)];   // un-swizzle (16-lane-const XOR)
  }
}

// ---- kernel 3: sum 32 chunk partials -> f32 fine histogram [128][128] ----
// 256 blocks x 256 thr (one word per thread; full-chip spread so each CU's
// slice is only 32KB of L2-resident reads — per-CU BW is the governing limit,
// R7 post-mortem). Integer adds: order-free, exact.
__global__ __launch_bounds__(256) void reduce_fine_kernel(const unsigned* __restrict__ part,
                                                          float2* __restrict__ fineF) {
  const int tid = threadIdx.x;
  const int b = blockIdx.x >> 5, sl = blockIdx.x & 31;
  const int w = sl * 256 + tid;                       // word in [0, 8192)
  const unsigned* src = part + ((size_t)b << 18) + w;
  unsigned lo = 0, hi = 0;
  #pragma unroll 8
  for (int c = 0; c < 32; ++c) {
    unsigned v = src[(size_t)c << 13];
    lo += v & 0xFFFFu; hi += v >> 16;
  }
  float2 o; o.x = (float)lo; o.y = (float)hi;
  fineF[(size_t)b * 8192 + w] = o;                    // fineG[b][128][128] flat
}

// ---- kernel 4 (fused tail): conv1 (fine-p axis, decimate x2) -> mid in LDS ->
//      conv2 (fine-t axis) -> marginals -> MI -> last-block final mean ----
__global__ __launch_bounds__(1024) void tail_kernel(const float* __restrict__ fineG,
                                                    float* __restrict__ mi,
                                                    unsigned* __restrict__ cnt,
                                                    float* __restrict__ out) {
  __shared__ float S[14608];   // [0,10304) mid[64][161] | [10304,14464) pxy[64][65]
                               // | 14464 px | 14528 py | 14592 wred
  const int tid = threadIdx.x, lane = tid & 63, wave = tid >> 6;
  const int b = blockIdx.x;

  // ---- phase A: conv along fine-p rows, decimate x2 -> S[0,10304) ----
  {
    const int ft = tid & 127, r = tid >> 7;
    const float* fb = fineG + ((size_t)b << 14) + ft;
    float v[47];
    #pragma unroll
    for (int t = 0; t < 47; ++t) {
      int fp = 16 * r - 16 + t;
      v[t] = ((unsigned)fp < 128u) ? fb[fp << 7] : 0.0f;
    }
    float acc[8];
    #pragma unroll
    for (int d = 0; d < 8; ++d) {
      float a = 0.0f;
      #pragma unroll
      for (int k = 0; k < 33; ++k) a += WK[k] * v[2 * d + k];
      acc[d] = a;
    }
    #pragma unroll
    for (int d = 0; d < 8; ++d)
      S[(8 * r + d) * MPW + ft + 16] = acc[d];
    // zero guard columns: 64 rows x (16 left + 17 right)
    #pragma unroll
    for (int ii = 0; ii < 3; ++ii) {
      int idx = ii * 1024 + tid;
      if (idx < 64 * 33) {
        int rr = idx / 33, cc = idx % 33;
        int col = cc < 16 ? cc : cc + 128;
        S[rr * MPW + col] = 0.0f;
      }
    }
  }
  __syncthreads();

  // ---- phase B: conv along fine-t axis -> pxy ----
  const int i = tid & 63, js = (tid >> 6) << 2;
  {
    float v[39];
    #pragma unroll
    for (int t = 0; t < 39; ++t) v[t] = S[i * MPW + 2 * js + t];
    float acc[4] = {0.0f, 0.0f, 0.0f, 0.0f};
    #pragma unroll
    for (int d = 0; d < 4; ++d)
      #pragma unroll
      for (int k = 0; k < 33; ++k) acc[d] += WK[k] * v[2 * d + k];
    const float invN = 1.0f / (float)NPIX;
    #pragma unroll
    for (int d = 0; d < 4; ++d) S[10304 + i * 65 + js + d] = acc[d] * invN;
  }
  __syncthreads();

  // marginals: wave w owns 4 rows + 4 cols (16-lane groups)
  {
    const int l16 = lane & 15, sub16 = lane >> 4;
    int row = 4 * wave + sub16;
    float s = 0.0f;
    #pragma unroll
    for (int k = 0; k < 4; ++k) s += S[10304 + row * 65 + l16 * 4 + k];
    #pragma unroll
    for (int off = 8; off; off >>= 1) s += __shfl_xor(s, off);
    if (l16 == 0) S[14464 + row] = s;     // px
    float t2 = 0.0f;
    #pragma unroll
    for (int k = 0; k < 4; ++k) t2 += S[10304 + (l16 * 4 + k) * 65 + row];
    #pragma unroll
    for (int off = 8; off; off >>= 1) t2 += __shfl_xor(t2, off);
    if (l16 == 0) S[14528 + row] = t2;    // py
  }
  __syncthreads();

  float a = 0.0f;
  #pragma unroll
  for (int r = 0; r < 4; ++r) {
    int e = r * 1024 + tid;
    int ii = e >> 6, jj = e & 63;
    float pv = S[10304 + ii * 65 + jj];
    float d = S[14464 + ii] * S[14528 + jj] + 1e-10f;
    a += pv * __logf((pv + 1e-10f) / d);
  }
  #pragma unroll
  for (int off = 32; off; off >>= 1) a += __shfl_xor(a, off);
  if (lane == 0) S[14592 + wave] = a;
  __syncthreads();

  if (tid == 0) {
    float s = 0.0f;
    #pragma unroll
    for (int w = 0; w < 16; ++w) s += S[14592 + w];
    atomicExch(&mi[b], s);                 // device-scope atomic store
    __threadfence();                       // release: mi visible before counter
    unsigned prev = atomicAdd(cnt, 1u);
    if (prev == NB - 1) {                  // last block finalizes
      __threadfence();                     // acquire
      float tot = 0.0f;
      #pragma unroll
      for (int k = 0; k < NB; ++k) tot += atomicAdd(&mi[k], 0.0f);  // atomic read
      out[0] = -(tot * (1.0f / NB));
      atomicExch(cnt, 0u);                 // self-reset (replay safety)
    }
  }
}

extern "C" void kernel_launch(void* const* d_in, const int* in_sizes, int n_in,
                              void* d_out, int out_size, void* d_ws, size_t ws_size,
                              hipStream_t stream) {
  const float* pred = (const float*)d_in[0];
  const float* tgt  = (const float*)d_in[1];
  float*    out  = (float*)d_out;
  float*    wsf  = (float*)d_ws;
  float2*   mm   = (float2*)d_ws;                      // 256 float2 in [0,512) floats
  float*    mi   = wsf + 512;                          // 8 floats
  unsigned* cnt  = (unsigned*)(wsf + 520);             // tail completion counter
  unsigned* part = (unsigned*)(wsf + HDR_FLOATS);      // NB*NCH*8192 words = 8MB
  float*    fineG = wsf + HDR_FLOATS + (size_t)NB * NCH * 8192;   // NB*16384 f32

  minmax_kernel     <<<256,      1024, 0, stream>>>(pred, tgt, mm, cnt);
  fine_hist_kernel  <<<NB * NCH, 1024, 0, stream>>>(pred, tgt, mm, part);
  reduce_fine_kernel<<<256,       256, 0, stream>>>(part, (float2*)fineG);
  tail_kernel       <<<NB,       1024, 0, stream>>>(fineG, mi, cnt, out);
}